// Round 14
// baseline (71.998 us; speedup 1.0000x reference)
//
#include <hip/hip_runtime.h>

// GBDT ensemble inference — R14: R13 + speculative both-children xs reads.
// Each fused pair-stage reads xs[parent], xs[loChild], xs[hiChild] in
// PARALLEL (record carries all three feature ids), removing one serial
// LDS link (~120-150cy) per stage from the dependent chain.
// B=32768, T=512, D=8, F=512, C=1.
//
// ws16 layout (int4 records):
//   PT0 [0,1024):      levels 0,1   (staged to LDS)
//   PT1 [1024,5120):   levels 2,3   (staged to LDS)
//   PT2 [5120,21504):  levels 4,5   (VMEM)
//   PT3 [21504,87040): level 6+leaf (VMEM)
// Pair rec: {f0|fL<<10|fR<<20, b0, bL, bR}; PT3 rec: {f6, b6, leafL, leafR}.
//
// Mapping: lane = row (0..31) + tree-group g (lane>>5); wave owns 32 trees;
// per step 8 trees, lane handles 4 consecutive; float4 leaf stores.
// LDS: xs(66KB) + pt0(16KB) + pt1(64KB) + rt(4KB) = 152 KB, 1 block/CU.

#define BB 32768
#define TT 512
#define FF 512
#define PADW 65536
#define ROWS 32
#define THREADS 1024
#define TPW 32
#define XSS 515           // odd stride: correlated-feature lanes spread banks

#define PT0_OFF 0
#define PT1_OFF 1024
#define PT2_OFF 5120
#define PT3_OFF 21504
#define N_REC   87040

__global__ __launch_bounds__(256) void build_tables_kernel(
    const int*   __restrict__ nodes_lv,
    const float* __restrict__ biases_lv,
    const float* __restrict__ leaf_nodes,
    int4*        __restrict__ ws16)
{
    const int i = blockIdx.x * 256 + threadIdx.x;
    if (i >= N_REC) return;

    int l, p, off;
    if (i < PT1_OFF)      { l = 0; off = PT0_OFF; }
    else if (i < PT2_OFF) { l = 2; off = PT1_OFF; }
    else if (i < PT3_OFF) { l = 4; off = PT2_OFF; }
    else {
        p = i - PT3_OFF;
        const int   f  = nodes_lv[6 * PADW + p];
        const float b  = biases_lv[6 * PADW + p];
        const float lL = leaf_nodes[2 * p];
        const float lR = leaf_nodes[2 * p + 1];
        ws16[i] = make_int4(f, __float_as_int(b),
                            __float_as_int(lL), __float_as_int(lR));
        return;
    }
    p = i - off;
    const int   f0 = nodes_lv[l * PADW + p];
    const float b0 = biases_lv[l * PADW + p];
    const int   fL = nodes_lv[(l + 1) * PADW + 2 * p];
    const int   fR = nodes_lv[(l + 1) * PADW + 2 * p + 1];
    const float bL = biases_lv[(l + 1) * PADW + 2 * p];
    const float bR = biases_lv[(l + 1) * PADW + 2 * p + 1];
    ws16[i] = make_int4(f0 | (fL << 10) | (fR << 20), __float_as_int(b0),
                        __float_as_int(bL), __float_as_int(bR));
}

// Speculative pair-stage: 3 parallel xs reads, then resolve both levels.
#define PAIR_STAGE(REC, P)                                                    \
    {                                                                         \
        const int   fp = (REC).x;                                             \
        const float xp = xrow[fp & 1023];                                     \
        const float xl = xrow[(fp >> 10) & 1023];                             \
        const float xh = xrow[(fp >> 20) & 1023];                             \
        const bool  g0 = xp >= __int_as_float((REC).y);                       \
        const float xc = g0 ? xh : xl;                                        \
        const float hc = g0 ? __int_as_float((REC).w) : __int_as_float((REC).z); \
        const bool  g1 = xc >= hc;                                            \
        (P) = 4 * (P) + 2 * (int)g0 + (int)g1;                                \
    }

__global__ __launch_bounds__(THREADS) void gbdt_walk_kernel(
    const float* __restrict__ x,
    const int*   __restrict__ root_nodes,
    const float* __restrict__ root_biases,
    const int4*  __restrict__ ws16,
    float*       __restrict__ out)
{
    __shared__ float xs[ROWS * XSS];   // 65,920 B
    __shared__ int4  pt0[1024];        // 16,384 B (levels 0,1)
    __shared__ int4  pt1[4096];        // 65,536 B (levels 2,3)
    __shared__ int2  rt[512];          //  4,096 B (root f,b)   total 151,936 B

    const int tid = threadIdx.x;
    const int b0  = blockIdx.x * ROWS;

    // ---- stage x rows (coalesced float4) ----
    const float4* __restrict__ xr = (const float4*)(x + (size_t)b0 * FF);
    #pragma unroll
    for (int i = 0; i < (ROWS * FF / 4) / THREADS; ++i) {   // 4 iters
        int fidx = i * THREADS + tid;
        int r = fidx >> 7, c4 = fidx & 127;
        float4 v = xr[fidx];
        float* d = &xs[r * XSS + (c4 << 2)];
        d[0] = v.x; d[1] = v.y; d[2] = v.z; d[3] = v.w;
    }
    // ---- stage PT0+PT1 (5120 int4, coalesced) ----
    #pragma unroll
    for (int i = 0; i < 5; ++i) {
        int idx = i * THREADS + tid;
        if (idx < 5120) {
            int4 v = ws16[idx];
            if (idx < 1024) pt0[idx] = v;
            else            pt1[idx - 1024] = v;
        }
    }
    // ---- stage roots ----
    if (tid < 512)
        rt[tid] = make_int2(root_nodes[tid], __float_as_int(root_biases[tid]));
    __syncthreads();

    const int wv   = tid >> 6;              // wave 0..15
    const int lane = tid & 63;
    const int row  = lane & 31;
    const int g    = lane >> 5;
    const int tb   = wv * TPW;
    const float* __restrict__ xrow = &xs[row * XSS];
    float* __restrict__ orow = out + (size_t)(b0 + row) * TT;

    #pragma unroll
    for (int s = 0; s < TPW / 8; ++s) {     // 4 steps, 8 trees each
        const int tbase = tb + 8 * s + 4 * g;
        int p[4];

        // ---- LDS macro-stage A: root + PT0 (levels 0,1) ----
        #pragma unroll
        for (int c = 0; c < 4; ++c) {
            const int t = tbase + c;
            const int2 rn = rt[t];
            const bool rb = xrow[rn.x] >= __int_as_float(rn.y);
            p[c] = 2 * t + (int)rb;
        }
        {
            int4 r0[4];
            #pragma unroll
            for (int c = 0; c < 4; ++c) r0[c] = pt0[p[c]];
            #pragma unroll
            for (int c = 0; c < 4; ++c) PAIR_STAGE(r0[c], p[c]);
        }
        // ---- LDS macro-stage B: PT1 (levels 2,3) ----
        {
            int4 r1[4];
            #pragma unroll
            for (int c = 0; c < 4; ++c) r1[c] = pt1[p[c]];
            #pragma unroll
            for (int c = 0; c < 4; ++c) PAIR_STAGE(r1[c], p[c]);
        }
        // ---- VMEM stage: PT2 (levels 4,5) ----
        {
            int4 r2[4];
            #pragma unroll
            for (int c = 0; c < 4; ++c) r2[c] = ws16[PT2_OFF + p[c]];
            #pragma unroll
            for (int c = 0; c < 4; ++c) PAIR_STAGE(r2[c], p[c]);
        }
        // ---- VMEM stage: PT3 (level 6 + leaf) ----
        int4 r3[4];
        #pragma unroll
        for (int c = 0; c < 4; ++c) r3[c] = ws16[PT3_OFF + p[c]];
        float v[4];
        #pragma unroll
        for (int c = 0; c < 4; ++c) {
            const bool gg = xrow[r3[c].x] >= __int_as_float(r3[c].y);
            v[c] = gg ? __int_as_float(r3[c].w) : __int_as_float(r3[c].z);
        }
        *(float4*)&orow[tbase] = make_float4(v[0], v[1], v[2], v[3]);
    }
}

// Fallback (ws too small): direct gathers from the original tables.
__global__ __launch_bounds__(THREADS) void gbdt_walk_fallback(
    const float* __restrict__ x,
    const int*   __restrict__ root_nodes,
    const float* __restrict__ root_biases,
    const int*   __restrict__ nodes_lv,
    const float* __restrict__ biases_lv,
    const float* __restrict__ leaf_nodes,
    float*       __restrict__ out)
{
    __shared__ float xs[ROWS * XSS];
    const int tid = threadIdx.x;
    const int b0  = blockIdx.x * ROWS;
    const float4* __restrict__ xr = (const float4*)(x + (size_t)b0 * FF);
    #pragma unroll
    for (int i = 0; i < (ROWS * FF / 4) / THREADS; ++i) {
        int fidx = i * THREADS + tid;
        int r = fidx >> 7, c4 = fidx & 127;
        float4 v = xr[fidx];
        float* d = &xs[r * XSS + (c4 << 2)];
        d[0] = v.x; d[1] = v.y; d[2] = v.z; d[3] = v.w;
    }
    __syncthreads();
    const int wv   = tid >> 6;
    const int lane = tid & 63;
    const int row  = lane & 31;
    const int g    = lane >> 5;
    const int tb   = wv * TPW;
    const float* __restrict__ xrow = &xs[row * XSS];
    float* __restrict__ orow = out + (size_t)(b0 + row) * TT;
    #pragma unroll
    for (int s = 0; s < TPW / 2; ++s) {
        const int t = tb + 2 * s + g;
        int p = 2 * t + (xrow[root_nodes[t]] >= root_biases[t] ? 1 : 0);
        #pragma unroll
        for (int l = 0; l < 7; ++l) {
            const int   f = nodes_lv[l * PADW + p];
            const float h = biases_lv[l * PADW + p];
            p = 2 * p + (xrow[f] >= h ? 1 : 0);
        }
        orow[t] = leaf_nodes[p];
    }
}

extern "C" void kernel_launch(void* const* d_in, const int* in_sizes, int n_in,
                              void* d_out, int out_size, void* d_ws, size_t ws_size,
                              hipStream_t stream) {
    const float* x            = (const float*)d_in[0];
    const int*   root_nodes   = (const int*)  d_in[1];
    const float* root_biases  = (const float*)d_in[2];
    const int*   nodes_lv     = (const int*)  d_in[4];
    const float* biases_lv    = (const float*)d_in[5];
    const float* leaf_nodes   = (const float*)d_in[6];
    float*       out          = (float*)d_out;

    dim3 grid(BB / ROWS);   // 1024 blocks
    dim3 block(THREADS);

    if (ws_size >= (size_t)N_REC * 16) {
        int4* ws16 = (int4*)d_ws;
        build_tables_kernel<<<(N_REC + 255) / 256, 256, 0, stream>>>(
            nodes_lv, biases_lv, leaf_nodes, ws16);
        gbdt_walk_kernel<<<grid, block, 0, stream>>>(
            x, root_nodes, root_biases, ws16, out);
    } else {
        gbdt_walk_fallback<<<grid, block, 0, stream>>>(
            x, root_nodes, root_biases, nodes_lv, biases_lv, leaf_nodes, out);
    }
}

// Round 15
// 67.913 us; speedup vs baseline: 1.0602x; 1.0602x over previous
//
#include <hip/hip_runtime.h>

// GBDT ensemble inference — R15: R13 + cross-step software pipeline.
// Pass 1: per step, LDS-only levels 0-3 -> p4, then IMMEDIATELY issue PT2
//         gathers (latency hides under next steps' LDS work).
// Pass 2: resolve PT2 per group (counted vmcnt), issue PT3 per group.
// Pass 3: resolve PT3 -> leaf stores.
// Exposed VMEM waits per wave: ~8 -> ~1-2. R14's speculative reads reverted.
// B=32768, T=512, D=8, F=512, C=1.
//
// ws16 layout (int4 records):
//   PT0 [0,1024):      levels 0,1   (staged to LDS)
//   PT1 [1024,5120):   levels 2,3   (staged to LDS)
//   PT2 [5120,21504):  levels 4,5   (VMEM)
//   PT3 [21504,87040): level 6+leaf (VMEM)
// Pair rec: {f0|fL<<10|fR<<20, b0, bL, bR}; PT3 rec: {f6, b6, leafL, leafR}.
//
// Mapping: lane = row (0..31) + tree-group g (lane>>5); wave owns 32 trees;
// lane owns 4 consecutive trees in each of 4 steps; float4 leaf stores.
// LDS: xs(66KB) + pt0(16KB) + pt1(64KB) + rt(4KB) = 152 KB, 1 block/CU.

#define BB 32768
#define TT 512
#define FF 512
#define PADW 65536
#define ROWS 32
#define THREADS 1024
#define TPW 32
#define XSS 515           // odd stride: correlated-feature lanes spread banks

#define PT0_OFF 0
#define PT1_OFF 1024
#define PT2_OFF 5120
#define PT3_OFF 21504
#define N_REC   87040

__global__ __launch_bounds__(256) void build_tables_kernel(
    const int*   __restrict__ nodes_lv,
    const float* __restrict__ biases_lv,
    const float* __restrict__ leaf_nodes,
    int4*        __restrict__ ws16)
{
    const int i = blockIdx.x * 256 + threadIdx.x;
    if (i >= N_REC) return;

    int l, p, off;
    if (i < PT1_OFF)      { l = 0; off = PT0_OFF; }
    else if (i < PT2_OFF) { l = 2; off = PT1_OFF; }
    else if (i < PT3_OFF) { l = 4; off = PT2_OFF; }
    else {
        p = i - PT3_OFF;
        const int   f  = nodes_lv[6 * PADW + p];
        const float b  = biases_lv[6 * PADW + p];
        const float lL = leaf_nodes[2 * p];
        const float lR = leaf_nodes[2 * p + 1];
        ws16[i] = make_int4(f, __float_as_int(b),
                            __float_as_int(lL), __float_as_int(lR));
        return;
    }
    p = i - off;
    const int   f0 = nodes_lv[l * PADW + p];
    const float b0 = biases_lv[l * PADW + p];
    const int   fL = nodes_lv[(l + 1) * PADW + 2 * p];
    const int   fR = nodes_lv[(l + 1) * PADW + 2 * p + 1];
    const float bL = biases_lv[(l + 1) * PADW + 2 * p];
    const float bR = biases_lv[(l + 1) * PADW + 2 * p + 1];
    ws16[i] = make_int4(f0 | (fL << 10) | (fR << 20), __float_as_int(b0),
                        __float_as_int(bL), __float_as_int(bR));
}

// Serial 2-level resolve (R13 form — lower LDS traffic than R14's speculative)
#define PAIR_RESOLVE(REC, P)                                                  \
    {                                                                         \
        const int   fp = (REC).x;                                             \
        const bool  g0 = xrow[fp & 1023] >= __int_as_float((REC).y);          \
        const int   f1 = g0 ? ((fp >> 20) & 1023) : ((fp >> 10) & 1023);      \
        const float h1 = g0 ? __int_as_float((REC).w) : __int_as_float((REC).z); \
        const bool  g1 = xrow[f1] >= h1;                                      \
        (P) = 4 * (P) + 2 * (int)g0 + (int)g1;                                \
    }

__global__ __launch_bounds__(THREADS, 4) void gbdt_walk_kernel(
    const float* __restrict__ x,
    const int*   __restrict__ root_nodes,
    const float* __restrict__ root_biases,
    const int4*  __restrict__ ws16,
    float*       __restrict__ out)
{
    __shared__ float xs[ROWS * XSS];   // 65,920 B
    __shared__ int4  pt0[1024];        // 16,384 B (levels 0,1)
    __shared__ int4  pt1[4096];        // 65,536 B (levels 2,3)
    __shared__ int2  rt[512];          //  4,096 B (root f,b)   total 151,936 B

    const int tid = threadIdx.x;
    const int b0  = blockIdx.x * ROWS;

    // ---- stage x rows (coalesced float4) ----
    const float4* __restrict__ xr = (const float4*)(x + (size_t)b0 * FF);
    #pragma unroll
    for (int i = 0; i < (ROWS * FF / 4) / THREADS; ++i) {   // 4 iters
        int fidx = i * THREADS + tid;
        int r = fidx >> 7, c4 = fidx & 127;
        float4 v = xr[fidx];
        float* d = &xs[r * XSS + (c4 << 2)];
        d[0] = v.x; d[1] = v.y; d[2] = v.z; d[3] = v.w;
    }
    // ---- stage PT0+PT1 (5120 int4, coalesced) ----
    #pragma unroll
    for (int i = 0; i < 5; ++i) {
        int idx = i * THREADS + tid;
        if (idx < 5120) {
            int4 v = ws16[idx];
            if (idx < 1024) pt0[idx] = v;
            else            pt1[idx - 1024] = v;
        }
    }
    // ---- stage roots ----
    if (tid < 512)
        rt[tid] = make_int2(root_nodes[tid], __float_as_int(root_biases[tid]));
    __syncthreads();

    const int wv   = tid >> 6;              // wave 0..15
    const int lane = tid & 63;
    const int row  = lane & 31;
    const int g    = lane >> 5;
    const int tb   = wv * TPW;
    const float* __restrict__ xrow = &xs[row * XSS];
    float* __restrict__ orow = out + (size_t)(b0 + row) * TT;

    int  p4[16];
    int4 r2[4][4];

    // ---- Pass 1: LDS levels 0-3 per step, issue PT2 gathers immediately ----
    #pragma unroll
    for (int s = 0; s < 4; ++s) {
        const int tbase = tb + 8 * s + 4 * g;
        #pragma unroll
        for (int c = 0; c < 4; ++c) {
            const int t = tbase + c;
            const int2 rn = rt[t];
            int p = 2 * t + (xrow[rn.x] >= __int_as_float(rn.y) ? 1 : 0);
            const int4 r0 = pt0[p];
            PAIR_RESOLVE(r0, p);
            const int4 r1 = pt1[p];
            PAIR_RESOLVE(r1, p);
            p4[4 * s + c] = p;
            r2[s][c] = ws16[PT2_OFF + p];   // VMEM issue, hidden under later LDS
        }
    }

    // ---- Pass 2: resolve PT2 per group, issue PT3 per group ----
    int4 r3[4][4];
    #pragma unroll
    for (int s = 0; s < 4; ++s) {
        #pragma unroll
        for (int c = 0; c < 4; ++c) {
            int p = p4[4 * s + c];
            PAIR_RESOLVE(r2[s][c], p);
            r3[s][c] = ws16[PT3_OFF + p];
        }
    }

    // ---- Pass 3: resolve PT3 -> leaf stores ----
    #pragma unroll
    for (int s = 0; s < 4; ++s) {
        const int tbase = tb + 8 * s + 4 * g;
        float v[4];
        #pragma unroll
        for (int c = 0; c < 4; ++c) {
            const int4 r = r3[s][c];
            const bool gg = xrow[r.x] >= __int_as_float(r.y);
            v[c] = gg ? __int_as_float(r.w) : __int_as_float(r.z);
        }
        *(float4*)&orow[tbase] = make_float4(v[0], v[1], v[2], v[3]);
    }
}

// Fallback (ws too small): direct gathers from the original tables.
__global__ __launch_bounds__(THREADS) void gbdt_walk_fallback(
    const float* __restrict__ x,
    const int*   __restrict__ root_nodes,
    const float* __restrict__ root_biases,
    const int*   __restrict__ nodes_lv,
    const float* __restrict__ biases_lv,
    const float* __restrict__ leaf_nodes,
    float*       __restrict__ out)
{
    __shared__ float xs[ROWS * XSS];
    const int tid = threadIdx.x;
    const int b0  = blockIdx.x * ROWS;
    const float4* __restrict__ xr = (const float4*)(x + (size_t)b0 * FF);
    #pragma unroll
    for (int i = 0; i < (ROWS * FF / 4) / THREADS; ++i) {
        int fidx = i * THREADS + tid;
        int r = fidx >> 7, c4 = fidx & 127;
        float4 v = xr[fidx];
        float* d = &xs[r * XSS + (c4 << 2)];
        d[0] = v.x; d[1] = v.y; d[2] = v.z; d[3] = v.w;
    }
    __syncthreads();
    const int wv   = tid >> 6;
    const int lane = tid & 63;
    const int row  = lane & 31;
    const int g    = lane >> 5;
    const int tb   = wv * TPW;
    const float* __restrict__ xrow = &xs[row * XSS];
    float* __restrict__ orow = out + (size_t)(b0 + row) * TT;
    #pragma unroll
    for (int s = 0; s < TPW / 2; ++s) {
        const int t = tb + 2 * s + g;
        int p = 2 * t + (xrow[root_nodes[t]] >= root_biases[t] ? 1 : 0);
        #pragma unroll
        for (int l = 0; l < 7; ++l) {
            const int   f = nodes_lv[l * PADW + p];
            const float h = biases_lv[l * PADW + p];
            p = 2 * p + (xrow[f] >= h ? 1 : 0);
        }
        orow[t] = leaf_nodes[p];
    }
}

extern "C" void kernel_launch(void* const* d_in, const int* in_sizes, int n_in,
                              void* d_out, int out_size, void* d_ws, size_t ws_size,
                              hipStream_t stream) {
    const float* x            = (const float*)d_in[0];
    const int*   root_nodes   = (const int*)  d_in[1];
    const float* root_biases  = (const float*)d_in[2];
    const int*   nodes_lv     = (const int*)  d_in[4];
    const float* biases_lv    = (const float*)d_in[5];
    const float* leaf_nodes   = (const float*)d_in[6];
    float*       out          = (float*)d_out;

    dim3 grid(BB / ROWS);   // 1024 blocks
    dim3 block(THREADS);

    if (ws_size >= (size_t)N_REC * 16) {
        int4* ws16 = (int4*)d_ws;
        build_tables_kernel<<<(N_REC + 255) / 256, 256, 0, stream>>>(
            nodes_lv, biases_lv, leaf_nodes, ws16);
        gbdt_walk_kernel<<<grid, block, 0, stream>>>(
            x, root_nodes, root_biases, ws16, out);
    } else {
        gbdt_walk_fallback<<<grid, block, 0, stream>>>(
            x, root_nodes, root_biases, nodes_lv, biases_lv, leaf_nodes, out);
    }
}